// Round 6
// baseline (584.576 us; speedup 1.0000x reference)
//
#include <hip/hip_runtime.h>
#include <hip/hip_bf16.h>

#define N_NODES 100000
#define N_EDGES 1600000
#define D_FEAT 256
#define HIDDEN 256
#define N_CLASSES 64

#define NBKT 391                // buckets of 256 nodes: 99999>>8 = 390
#define TILE 4096               // edges per bin_scatter block
#define CAP  8192               // bucket_fill LDS staging (mean 4093, sigma 64)

typedef __attribute__((ext_vector_type(8))) short bf16x8;
typedef __attribute__((ext_vector_type(4))) float f32x4;
typedef __attribute__((ext_vector_type(4))) ushort u16x4;

__device__ inline float b2f(ushort u) {
    unsigned v = ((unsigned)u) << 16;
    float f; __builtin_memcpy(&f, &v, 4); return f;
}
__device__ inline ushort f2b(float f) {   // RNE
    unsigned u; __builtin_memcpy(&u, &f, 4);
    unsigned r = (u + 0x7fffu + ((u >> 16) & 1u)) >> 16;
    return (ushort)r;
}

// ---------------- CSR build: bucketed two-phase ----------------
__global__ __launch_bounds__(256)
void bin_count(const int* __restrict__ cols, int* bcnt, int nE) {
    __shared__ int h[NBKT];
    int t = threadIdx.x;
    for (int i = t; i < NBKT; i += 256) h[i] = 0;
    __syncthreads();
    for (long e = (long)blockIdx.x * 256 + t; e < nE; e += (long)gridDim.x * 256)
        atomicAdd(&h[cols[e] >> 8], 1);
    __syncthreads();
    for (int i = t; i < NBKT; i += 256)
        if (h[i]) atomicAdd(&bcnt[i], h[i]);
}

__global__ __launch_bounds__(256)
void bucket_scan(const int* __restrict__ bcnt, int* __restrict__ bbase,
                 int* __restrict__ bcur, int* __restrict__ offsets) {
    __shared__ int sd[256];
    int t = threadIdx.x;
    int i0 = 2 * t, i1 = 2 * t + 1;
    int a = (i0 < NBKT) ? bcnt[i0] : 0;
    int b = (i1 < NBKT) ? bcnt[i1] : 0;
    int s = a + b;
    sd[t] = s; __syncthreads();
    #pragma unroll
    for (int off = 1; off < 256; off <<= 1) {
        int v = (t >= off) ? sd[t - off] : 0;
        __syncthreads();
        sd[t] += v;
        __syncthreads();
    }
    int ex = sd[t] - s;
    if (i0 <= NBKT) bbase[i0] = ex;
    if (i0 < NBKT)  bcur[i0] = ex;
    if (i1 <= NBKT) bbase[i1] = ex + a;
    if (i1 < NBKT)  bcur[i1] = ex + a;
    if (t == 0) offsets[N_NODES] = N_EDGES;
}

// tile -> LDS sort by bucket -> batched reservation -> packed contiguous writes
__global__ __launch_bounds__(256)
void bin_scatter(const int* __restrict__ rows, const int* __restrict__ cols,
                 int* bcur, unsigned* __restrict__ bins, int nE)
{
    __shared__ unsigned recs[TILE];
    __shared__ ushort bos[TILE];
    __shared__ int hist[NBKT], excl[NBKT], cursor[NBKT], gbase[NBKT];
    __shared__ int sd[256];
    int t = threadIdx.x;
    long e0 = (long)blockIdx.x * TILE;
    int cnt = (int)min((long)TILE, (long)nE - e0);
    for (int i = t; i < NBKT; i += 256) hist[i] = 0;
    __syncthreads();
    int myrow[TILE / 256], mycol[TILE / 256];
    #pragma unroll
    for (int k = 0; k < TILE / 256; ++k) {
        int i = k * 256 + t;
        if (i < cnt) {
            myrow[k] = rows[e0 + i];
            mycol[k] = cols[e0 + i];
            atomicAdd(&hist[mycol[k] >> 8], 1);
        }
    }
    __syncthreads();
    {
        int i0 = 2 * t, i1 = 2 * t + 1;
        int a = (i0 < NBKT) ? hist[i0] : 0;
        int b = (i1 < NBKT) ? hist[i1] : 0;
        int s = a + b;
        sd[t] = s; __syncthreads();
        #pragma unroll
        for (int off = 1; off < 256; off <<= 1) {
            int v = (t >= off) ? sd[t - off] : 0;
            __syncthreads();
            sd[t] += v;
            __syncthreads();
        }
        int ex = sd[t] - s;
        if (i0 < NBKT) { excl[i0] = ex;     cursor[i0] = ex; }
        if (i1 < NBKT) { excl[i1] = ex + a; cursor[i1] = ex + a; }
    }
    __syncthreads();
    #pragma unroll
    for (int k = 0; k < TILE / 256; ++k) {
        int i = k * 256 + t;
        if (i < cnt) {
            int b = mycol[k] >> 8;
            int s = atomicAdd(&cursor[b], 1);
            recs[s] = ((unsigned)(mycol[k] & 255) << 24) | (unsigned)myrow[k];
            bos[s] = (ushort)b;
        }
    }
    __syncthreads();
    for (int i = t; i < NBKT; i += 256)
        if (hist[i] > 0) gbase[i] = atomicAdd(&bcur[i], hist[i]);
    __syncthreads();
    for (int i = t; i < cnt; i += 256) {
        int b = bos[i];
        bins[gbase[b] + (i - excl[b])] = recs[i];
    }
}

// one block per bucket: degrees -> dinv/offsets; LDS-staged coalesced esrc
__global__ __launch_bounds__(256)
void bucket_fill(const unsigned* __restrict__ bins, const int* __restrict__ bbase,
                 int* __restrict__ offsets, float* __restrict__ dinv,
                 int* __restrict__ esrc)
{
    int b = blockIdx.x, t = threadIdx.x;
    int s0 = bbase[b], s1 = bbase[b + 1];
    int len = s1 - s0;
    __shared__ int cnt[256];
    __shared__ int sd[256];
    __shared__ int cur[256];
    __shared__ int stage[CAP];
    cnt[t] = 0;
    __syncthreads();
    for (int i = t; i < len; i += 256) atomicAdd(&cnt[bins[s0 + i] >> 24], 1);
    __syncthreads();
    int c = cnt[t];
    sd[t] = c; __syncthreads();
    #pragma unroll
    for (int off = 1; off < 256; off <<= 1) {
        int v = (t >= off) ? sd[t - off] : 0;
        __syncthreads();
        sd[t] += v;
        __syncthreads();
    }
    int ex = sd[t] - c;
    cur[t] = ex;
    int node = b * 256 + t;
    if (node < N_NODES) {
        offsets[node] = s0 + ex;
        dinv[node] = rsqrtf(1.0f + (float)c);
    }
    __syncthreads();
    if (len <= CAP) {
        for (int i = t; i < len; i += 256) {
            unsigned r = bins[s0 + i];
            int p = atomicAdd(&cur[r >> 24], 1);
            stage[p] = (int)(r & 0xFFFFFFu);
        }
        __syncthreads();
        for (int i = t; i < len; i += 256) esrc[s0 + i] = stage[i];
    } else {   // statistically unreachable fallback (correctness guard)
        for (int i = t; i < len; i += 256) {
            unsigned r = bins[s0 + i];
            int p = atomicAdd(&cur[r >> 24], 1);
            esrc[s0 + p] = (int)(r & 0xFFFFFFu);
        }
    }
}

// ---------------- W1 (hi/lo) + W2 -> fragment-ordered bf16 + bcnt zero ------
// Launched FIRST; blocks 0/1 also zero bcnt (saves the zero_bcnt dispatch).
__global__ __launch_bounds__(256)
void fragw(const float* __restrict__ W1, ushort* __restrict__ wfh,
           ushort* __restrict__ wfl,
           const float* __restrict__ W2, ushort* __restrict__ wf2,
           int* __restrict__ bcnt) {
    int t = blockIdx.x * 256 + threadIdx.x;      // 10240 total
    if (t < NBKT) bcnt[t] = 0;
    int lane = t & 63;
    int m = lane & 15, quad = lane >> 4;
    if (t < 8192) {                               // W1: 8 ks x 16 nb x 64 lanes
        int ks = t >> 10, nb = (t >> 6) & 15;
        ushort h8[8], l8[8];
        #pragma unroll
        for (int j = 0; j < 8; ++j) {
            int k = ks * 32 + quad * 8 + j;
            float w = W1[k * HIDDEN + nb * 16 + m];
            h8[j] = f2b(w);
            l8[j] = f2b(w - b2f(h8[j]));
        }
        long off = ((long)(ks * 16 + nb) * 64 + lane) * 8;
        *(ushort4*)&wfh[off]     = make_ushort4(h8[0], h8[1], h8[2], h8[3]);
        *(ushort4*)&wfh[off + 4] = make_ushort4(h8[4], h8[5], h8[6], h8[7]);
        *(ushort4*)&wfl[off]     = make_ushort4(l8[0], l8[1], l8[2], l8[3]);
        *(ushort4*)&wfl[off + 4] = make_ushort4(l8[4], l8[5], l8[6], l8[7]);
    } else {                                      // W2: 8 ks x 4 nb x 64 lanes
        int u = t - 8192;
        int ks = u >> 8, nb = (u >> 6) & 3;
        ushort h8[8];
        #pragma unroll
        for (int j = 0; j < 8; ++j) {
            int k = ks * 32 + quad * 8 + j;
            h8[j] = f2b(W2[k * N_CLASSES + nb * 16 + m]);
        }
        long off = ((long)(ks * 4 + nb) * 64 + lane) * 8;
        *(ushort4*)&wf2[off]     = make_ushort4(h8[0], h8[1], h8[2], h8[3]);
        *(ushort4*)&wf2[off + 4] = make_ushort4(h8[4], h8[5], h8[6], h8[7]);
    }
}

// ---------------- GEMM1: hs = dinv[row] * (x @ W1), fused split, full-width -
// One block = 128 rows x 256 cols (ALL of HIDDEN), grid=782: each x element
// is loaded+converted exactly once, by its owning thread, into XOR-swizzled
// bf16 hi/lo LDS tiles; 4 waves (2x2) consume fragments. Identical
// truncate-hi / RNE-lo split and 3-product MFMA order as prior rounds ->
// bit-identical results.
__global__ __launch_bounds__(256)
void gemm1_mfma(const float* __restrict__ x,
                const ushort* __restrict__ wfh, const ushort* __restrict__ wfl,
                const float* __restrict__ dinv, ushort* __restrict__ hs)
{
    __shared__ u16x4 lh[1024];                   // [128 rows][8 slots] 8 KB hi
    __shared__ u16x4 ll[1024];                   // 8 KB lo
    int tid = threadIdx.x;
    int lane = tid & 63;
    int wm = (tid >> 6) & 1;                     // row half
    int wn = (tid >> 7) & 1;                     // col half
    int row0 = blockIdx.x * 128 + wm * 64;
    int nb0 = wn * 8;
    int m = lane & 15, quad = lane >> 4;

    // staging geometry: 4 chunks/thread; chunk j -> idx=j*256+tid
    int sslot[4];
    const float* gp[4];
    #pragma unroll
    for (int j = 0; j < 4; ++j) {
        int idx = j * 256 + tid;
        int lr = idx >> 3, cg = idx & 7;
        sslot[j] = lr * 8 + (cg ^ (lr & 7));
        int gr = min(blockIdx.x * 128 + lr, N_NODES - 1);   // clamp pad rows
        gp[j] = x + (long)gr * D_FEAT + cg * 4;
    }

    f32x4 acc[4][8];
    #pragma unroll
    for (int i = 0; i < 4; ++i)
        #pragma unroll
        for (int j = 0; j < 8; ++j) acc[i][j] = (f32x4){0.f, 0.f, 0.f, 0.f};

    f32x4 stg[4];
    #pragma unroll
    for (int j = 0; j < 4; ++j) stg[j] = *(const f32x4*)(gp[j]);   // ks=0

    for (int ks = 0; ks < 8; ++ks) {
        // convert this thread's 16 elems (once per element) and write LDS
        #pragma unroll
        for (int j = 0; j < 4; ++j) {
            u16x4 h, l;
            #pragma unroll
            for (int c = 0; c < 4; ++c) {
                float v = stg[j][c];
                unsigned u; __builtin_memcpy(&u, &v, 4);
                ushort hh = (ushort)(u >> 16);           // truncate hi
                h[c] = hh;
                l[c] = f2b(v - b2f(hh));                 // exact remainder, RNE
            }
            lh[sslot[j]] = h;
            ll[sslot[j]] = l;
        }
        __syncthreads();
        if (ks < 7) {
            #pragma unroll
            for (int j = 0; j < 4; ++j)
                stg[j] = *(const f32x4*)(gp[j] + (ks + 1) * 32);   // prefetch
        }
        bf16x8 ah[4], al[4];
        #pragma unroll
        for (int mf = 0; mf < 4; ++mf) {
            int r = wm * 64 + mf * 16 + m;
            int sw = r & 7;
            u16x4 h0 = lh[r * 8 + ((quad * 2)     ^ sw)];
            u16x4 h1 = lh[r * 8 + ((quad * 2 + 1) ^ sw)];
            u16x4 l0 = ll[r * 8 + ((quad * 2)     ^ sw)];
            u16x4 l1 = ll[r * 8 + ((quad * 2 + 1) ^ sw)];
            ah[mf] = (bf16x8){(short)h0[0], (short)h0[1], (short)h0[2], (short)h0[3],
                              (short)h1[0], (short)h1[1], (short)h1[2], (short)h1[3]};
            al[mf] = (bf16x8){(short)l0[0], (short)l0[1], (short)l0[2], (short)l0[3],
                              (short)l1[0], (short)l1[1], (short)l1[2], (short)l1[3]};
        }
        #pragma unroll
        for (int nbl = 0; nbl < 8; ++nbl) {
            long boff = ((long)(ks * 16 + nb0 + nbl) * 64 + lane) * 8;
            bf16x8 bh = *(const bf16x8*)(wfh + boff);
            bf16x8 bl = *(const bf16x8*)(wfl + boff);
            #pragma unroll
            for (int mf = 0; mf < 4; ++mf) {
                acc[mf][nbl] = __builtin_amdgcn_mfma_f32_16x16x32_bf16(ah[mf], bh, acc[mf][nbl], 0, 0, 0);
                acc[mf][nbl] = __builtin_amdgcn_mfma_f32_16x16x32_bf16(ah[mf], bl, acc[mf][nbl], 0, 0, 0);
                acc[mf][nbl] = __builtin_amdgcn_mfma_f32_16x16x32_bf16(al[mf], bh, acc[mf][nbl], 0, 0, 0);
            }
        }
        __syncthreads();
    }

    #pragma unroll
    for (int mf = 0; mf < 4; ++mf)
        #pragma unroll
        for (int reg = 0; reg < 4; ++reg) {
            int row = row0 + mf * 16 + quad * 4 + reg;
            if (row < N_NODES) {
                float dv = dinv[row];
                #pragma unroll
                for (int nbl = 0; nbl < 8; ++nbl)
                    hs[(long)row * HIDDEN + (nb0 + nbl) * 16 + m] = f2b(acc[mf][nbl][reg] * dv);
            }
        }
}

// ---------------- GEMM2: h2 = r1s @ W2 (bf16 single) ----------------
__global__ __launch_bounds__(256)
void gemm2_mfma(const ushort* __restrict__ r1s, const ushort* __restrict__ wf,
                ushort* __restrict__ h2)
{
    int tid = threadIdx.x;
    int wv = tid >> 6, lane = tid & 63;
    int row0 = blockIdx.x * 256 + wv * 64;
    int m = lane & 15, quad = lane >> 4;

    f32x4 acc[4][4];
    #pragma unroll
    for (int i = 0; i < 4; ++i)
        #pragma unroll
        for (int j = 0; j < 4; ++j) acc[i][j] = (f32x4){0.f, 0.f, 0.f, 0.f};

    for (int ks = 0; ks < 8; ++ks) {
        bf16x8 a[4];
        #pragma unroll
        for (int mf = 0; mf < 4; ++mf) {
            long r = (long)(row0 + mf * 16 + m);
            a[mf] = *(const bf16x8*)(r1s + r * HIDDEN + ks * 32 + quad * 8);
        }
        #pragma unroll
        for (int nb = 0; nb < 4; ++nb) {
            bf16x8 b = *(const bf16x8*)(wf + ((long)(ks * 4 + nb) * 64 + lane) * 8);
            #pragma unroll
            for (int mf = 0; mf < 4; ++mf)
                acc[mf][nb] = __builtin_amdgcn_mfma_f32_16x16x32_bf16(a[mf], b, acc[mf][nb], 0, 0, 0);
        }
    }

    #pragma unroll
    for (int mf = 0; mf < 4; ++mf)
        #pragma unroll
        for (int reg = 0; reg < 4; ++reg) {
            int row = row0 + mf * 16 + quad * 4 + reg;
            if (row < N_NODES) {
                #pragma unroll
                for (int nb = 0; nb < 4; ++nb)
                    h2[(long)row * N_CLASSES + nb * 16 + m] = f2b(acc[mf][nb][reg]);
            }
        }
}

// ---------------- aggregate 256 feats bf16, unroll 8 ----------------
__global__ __launch_bounds__(256)
void agg256(const ushort* __restrict__ src, const int* __restrict__ offsets,
            const int* __restrict__ esrc, const float* __restrict__ dinv,
            const float* __restrict__ b1, ushort* __restrict__ dst)
{
    int wave = threadIdx.x >> 6, lane = threadIdx.x & 63;
    int v = blockIdx.x * 4 + wave;
    int c = lane << 2;
    ushort4 s = *(const ushort4*)&src[(long)v * 256 + c];
    float a0 = b2f(s.x), a1 = b2f(s.y), a2 = b2f(s.z), a3 = b2f(s.w);
    int e = offsets[v], end = offsets[v + 1];
    for (; e + 8 <= end; e += 8) {
        ushort4 u[8];
        #pragma unroll
        for (int j = 0; j < 8; ++j)
            u[j] = *(const ushort4*)&src[(long)esrc[e + j] * 256 + c];
        #pragma unroll
        for (int j = 0; j < 8; ++j) {
            a0 += b2f(u[j].x); a1 += b2f(u[j].y);
            a2 += b2f(u[j].z); a3 += b2f(u[j].w);
        }
    }
    for (; e < end; ++e) {
        ushort4 u = *(const ushort4*)&src[(long)esrc[e] * 256 + c];
        a0 += b2f(u.x); a1 += b2f(u.y); a2 += b2f(u.z); a3 += b2f(u.w);
    }
    float dv = dinv[v];
    float4 bb = *(const float4*)&b1[c];
    float r0 = dv * fmaxf(fmaf(dv, a0, bb.x), 0.f);
    float r1 = dv * fmaxf(fmaf(dv, a1, bb.y), 0.f);
    float r2 = dv * fmaxf(fmaf(dv, a2, bb.z), 0.f);
    float r3 = dv * fmaxf(fmaf(dv, a3, bb.w), 0.f);
    *(ushort4*)&dst[(long)v * 256 + c] = make_ushort4(f2b(r0), f2b(r1), f2b(r2), f2b(r3));
}

// ---------------- aggregate 64 feats bf16 -> fp32 out, unroll 8 -------------
__global__ __launch_bounds__(256)
void agg64b(const ushort* __restrict__ src, const int* __restrict__ offsets,
            const int* __restrict__ esrc, const float* __restrict__ dinv,
            const float* __restrict__ b2, float* __restrict__ out)
{
    int wave = threadIdx.x >> 6, lane = threadIdx.x & 63;
    int v = blockIdx.x * 4 + wave;
    float acc = b2f(src[(long)v * 64 + lane]);
    int e = offsets[v], end = offsets[v + 1];
    for (; e + 8 <= end; e += 8) {
        float a[8];
        #pragma unroll
        for (int j = 0; j < 8; ++j)
            a[j] = b2f(src[(long)esrc[e + j] * 64 + lane]);
        acc += ((a[0] + a[1]) + (a[2] + a[3])) + ((a[4] + a[5]) + (a[6] + a[7]));
    }
    for (; e < end; ++e) acc += b2f(src[(long)esrc[e] * 64 + lane]);
    out[(long)v * 64 + lane] = fmaf(dinv[v], acc, b2[lane]);
}

// ---------------- workspace layout (bytes, 16-aligned) ----------------
#define WS_DINV   0UL            // 400,000
#define WS_OFFS   400000UL       // 400,004
#define WS_BCNT   800016UL       // 391*4
#define WS_BBASE  801584UL       // 392*4
#define WS_BCUR   803152UL       // 391*4
#define WS_ESRC   804720UL       // 6,400,000
#define WS_BINS   7204720UL      // 6,400,000
#define WS_WF1H   13604720UL     // 131,072
#define WS_WF1L   13735792UL     // 131,072
#define WS_WF2    13866864UL     // 32,768
#define WS_HS1    13899632UL     // 51,216,384
#define WS_R1S    65148784UL     // 51,216,384
#define WS_H2     116397936UL    // 12,804,096 -> end ~129.2 MB

extern "C" void kernel_launch(void* const* d_in, const int* in_sizes, int n_in,
                              void* d_out, int out_size, void* d_ws, size_t ws_size,
                              hipStream_t stream)
{
    const float* x  = (const float*)d_in[0];
    const int*   ei = (const int*)d_in[1];
    const float* W1 = (const float*)d_in[2];
    const float* b1 = (const float*)d_in[3];
    const float* W2 = (const float*)d_in[4];
    const float* b2 = (const float*)d_in[5];
    float* out = (float*)d_out;

    const int* rows = ei;            // sources
    const int* cols = ei + N_EDGES;  // targets

    char* ws = (char*)d_ws;
    float*    dinv    = (float*)(ws + WS_DINV);
    int*      offsets = (int*)(ws + WS_OFFS);
    int*      bcnt    = (int*)(ws + WS_BCNT);
    int*      bbase   = (int*)(ws + WS_BBASE);
    int*      bcur    = (int*)(ws + WS_BCUR);
    int*      esrc    = (int*)(ws + WS_ESRC);
    unsigned* bins    = (unsigned*)(ws + WS_BINS);
    ushort*   wf1h    = (ushort*)(ws + WS_WF1H);
    ushort*   wf1l    = (ushort*)(ws + WS_WF1L);
    ushort*   wf2     = (ushort*)(ws + WS_WF2);
    ushort*   hs1     = (ushort*)(ws + WS_HS1);
    ushort*   r1s     = (ushort*)(ws + WS_R1S);
    ushort*   h2      = (ushort*)(ws + WS_H2);

    // --- weight fragment prep (also zeros bcnt; launched first) ---
    fragw<<<40, 256, 0, stream>>>(W1, wf1h, wf1l, W2, wf2, bcnt);

    // --- CSR build (bucketed) ---
    bin_count<<<512, 256, 0, stream>>>(cols, bcnt, N_EDGES);
    bucket_scan<<<1, 256, 0, stream>>>(bcnt, bbase, bcur, offsets);
    bin_scatter<<<(N_EDGES + TILE - 1) / TILE, 256, 0, stream>>>(rows, cols, bcur, bins, N_EDGES);
    bucket_fill<<<NBKT, 256, 0, stream>>>(bins, bbase, offsets, dinv, esrc);

    const int agg_grid = N_NODES / 4;

    // --- layer 1 ---
    gemm1_mfma<<<(N_NODES + 127) / 128, 256, 0, stream>>>(x, wf1h, wf1l, dinv, hs1);
    agg256<<<agg_grid, 256, 0, stream>>>(hs1, offsets, esrc, dinv, b1, r1s);

    // --- layer 2 ---
    gemm2_mfma<<<(N_NODES + 255) / 256, 256, 0, stream>>>(r1s, wf2, h2);
    agg64b<<<agg_grid, 256, 0, stream>>>(h2, offsets, esrc, dinv, b2, out);
}

// Round 7
// 515.684 us; speedup vs baseline: 1.1336x; 1.1336x over previous
//
#include <hip/hip_runtime.h>
#include <hip/hip_bf16.h>

#define N_NODES 100000
#define N_EDGES 1600000
#define D_FEAT 256
#define HIDDEN 256
#define N_CLASSES 64

#define NBKT 391                // buckets of 256 nodes: 99999>>8 = 390
#define TILE 4096               // edges per bin_scatter block
#define CAP  8192               // bucket_fill LDS staging (mean 4093, sigma 64)

typedef __attribute__((ext_vector_type(8))) short bf16x8;
typedef __attribute__((ext_vector_type(4))) float f32x4;

__device__ inline float b2f(ushort u) {
    unsigned v = ((unsigned)u) << 16;
    float f; __builtin_memcpy(&f, &v, 4); return f;
}
__device__ inline ushort f2b(float f) {   // RNE
    unsigned u; __builtin_memcpy(&u, &f, 4);
    unsigned r = (u + 0x7fffu + ((u >> 16) & 1u)) >> 16;
    return (ushort)r;
}

// ---------------- CSR build: bucketed two-phase ----------------
__global__ __launch_bounds__(256)
void bin_count(const int* __restrict__ cols, int* bcnt, int nE) {
    __shared__ int h[NBKT];
    int t = threadIdx.x;
    for (int i = t; i < NBKT; i += 256) h[i] = 0;
    __syncthreads();
    for (long e = (long)blockIdx.x * 256 + t; e < nE; e += (long)gridDim.x * 256)
        atomicAdd(&h[cols[e] >> 8], 1);
    __syncthreads();
    for (int i = t; i < NBKT; i += 256)
        if (h[i]) atomicAdd(&bcnt[i], h[i]);
}

__global__ __launch_bounds__(256)
void bucket_scan(const int* __restrict__ bcnt, int* __restrict__ bbase,
                 int* __restrict__ bcur, int* __restrict__ offsets) {
    __shared__ int sd[256];
    int t = threadIdx.x;
    int i0 = 2 * t, i1 = 2 * t + 1;
    int a = (i0 < NBKT) ? bcnt[i0] : 0;
    int b = (i1 < NBKT) ? bcnt[i1] : 0;
    int s = a + b;
    sd[t] = s; __syncthreads();
    #pragma unroll
    for (int off = 1; off < 256; off <<= 1) {
        int v = (t >= off) ? sd[t - off] : 0;
        __syncthreads();
        sd[t] += v;
        __syncthreads();
    }
    int ex = sd[t] - s;
    if (i0 <= NBKT) bbase[i0] = ex;
    if (i0 < NBKT)  bcur[i0] = ex;
    if (i1 <= NBKT) bbase[i1] = ex + a;
    if (i1 < NBKT)  bcur[i1] = ex + a;
    if (t == 0) offsets[N_NODES] = N_EDGES;
}

// tile -> LDS sort by bucket -> batched reservation -> packed contiguous writes
__global__ __launch_bounds__(256)
void bin_scatter(const int* __restrict__ rows, const int* __restrict__ cols,
                 int* bcur, unsigned* __restrict__ bins, int nE)
{
    __shared__ unsigned recs[TILE];
    __shared__ ushort bos[TILE];
    __shared__ int hist[NBKT], excl[NBKT], cursor[NBKT], gbase[NBKT];
    __shared__ int sd[256];
    int t = threadIdx.x;
    long e0 = (long)blockIdx.x * TILE;
    int cnt = (int)min((long)TILE, (long)nE - e0);
    for (int i = t; i < NBKT; i += 256) hist[i] = 0;
    __syncthreads();
    int myrow[TILE / 256], mycol[TILE / 256];
    #pragma unroll
    for (int k = 0; k < TILE / 256; ++k) {
        int i = k * 256 + t;
        if (i < cnt) {
            myrow[k] = rows[e0 + i];
            mycol[k] = cols[e0 + i];
            atomicAdd(&hist[mycol[k] >> 8], 1);
        }
    }
    __syncthreads();
    {
        int i0 = 2 * t, i1 = 2 * t + 1;
        int a = (i0 < NBKT) ? hist[i0] : 0;
        int b = (i1 < NBKT) ? hist[i1] : 0;
        int s = a + b;
        sd[t] = s; __syncthreads();
        #pragma unroll
        for (int off = 1; off < 256; off <<= 1) {
            int v = (t >= off) ? sd[t - off] : 0;
            __syncthreads();
            sd[t] += v;
            __syncthreads();
        }
        int ex = sd[t] - s;
        if (i0 < NBKT) { excl[i0] = ex;     cursor[i0] = ex; }
        if (i1 < NBKT) { excl[i1] = ex + a; cursor[i1] = ex + a; }
    }
    __syncthreads();
    #pragma unroll
    for (int k = 0; k < TILE / 256; ++k) {
        int i = k * 256 + t;
        if (i < cnt) {
            int b = mycol[k] >> 8;
            int s = atomicAdd(&cursor[b], 1);
            recs[s] = ((unsigned)(mycol[k] & 255) << 24) | (unsigned)myrow[k];
            bos[s] = (ushort)b;
        }
    }
    __syncthreads();
    for (int i = t; i < NBKT; i += 256)
        if (hist[i] > 0) gbase[i] = atomicAdd(&bcur[i], hist[i]);
    __syncthreads();
    for (int i = t; i < cnt; i += 256) {
        int b = bos[i];
        bins[gbase[b] + (i - excl[b])] = recs[i];
    }
}

// one block per bucket: degrees -> dinv/offsets; LDS-staged coalesced esrc
__global__ __launch_bounds__(256)
void bucket_fill(const unsigned* __restrict__ bins, const int* __restrict__ bbase,
                 int* __restrict__ offsets, float* __restrict__ dinv,
                 int* __restrict__ esrc)
{
    int b = blockIdx.x, t = threadIdx.x;
    int s0 = bbase[b], s1 = bbase[b + 1];
    int len = s1 - s0;
    __shared__ int cnt[256];
    __shared__ int sd[256];
    __shared__ int cur[256];
    __shared__ int stage[CAP];
    cnt[t] = 0;
    __syncthreads();
    for (int i = t; i < len; i += 256) atomicAdd(&cnt[bins[s0 + i] >> 24], 1);
    __syncthreads();
    int c = cnt[t];
    sd[t] = c; __syncthreads();
    #pragma unroll
    for (int off = 1; off < 256; off <<= 1) {
        int v = (t >= off) ? sd[t - off] : 0;
        __syncthreads();
        sd[t] += v;
        __syncthreads();
    }
    int ex = sd[t] - c;
    cur[t] = ex;
    int node = b * 256 + t;
    if (node < N_NODES) {
        offsets[node] = s0 + ex;
        dinv[node] = rsqrtf(1.0f + (float)c);
    }
    __syncthreads();
    if (len <= CAP) {
        for (int i = t; i < len; i += 256) {
            unsigned r = bins[s0 + i];
            int p = atomicAdd(&cur[r >> 24], 1);
            stage[p] = (int)(r & 0xFFFFFFu);
        }
        __syncthreads();
        for (int i = t; i < len; i += 256) esrc[s0 + i] = stage[i];
    } else {   // statistically unreachable fallback (correctness guard)
        for (int i = t; i < len; i += 256) {
            unsigned r = bins[s0 + i];
            int p = atomicAdd(&cur[r >> 24], 1);
            esrc[s0 + p] = (int)(r & 0xFFFFFFu);
        }
    }
}

// ---------------- W1 (hi/lo) + W2 -> fragment-ordered bf16 + bcnt zero ------
// Launched FIRST; low blocks also zero bcnt (saves the zero_bcnt dispatch).
__global__ __launch_bounds__(256)
void fragw(const float* __restrict__ W1, ushort* __restrict__ wfh,
           ushort* __restrict__ wfl,
           const float* __restrict__ W2, ushort* __restrict__ wf2,
           int* __restrict__ bcnt) {
    int t = blockIdx.x * 256 + threadIdx.x;      // 10240 total
    if (t < NBKT) bcnt[t] = 0;
    int lane = t & 63;
    int m = lane & 15, quad = lane >> 4;
    if (t < 8192) {                               // W1: 8 ks x 16 nb x 64 lanes
        int ks = t >> 10, nb = (t >> 6) & 15;
        ushort h8[8], l8[8];
        #pragma unroll
        for (int j = 0; j < 8; ++j) {
            int k = ks * 32 + quad * 8 + j;
            float w = W1[k * HIDDEN + nb * 16 + m];
            h8[j] = f2b(w);
            l8[j] = f2b(w - b2f(h8[j]));
        }
        long off = ((long)(ks * 16 + nb) * 64 + lane) * 8;
        *(ushort4*)&wfh[off]     = make_ushort4(h8[0], h8[1], h8[2], h8[3]);
        *(ushort4*)&wfh[off + 4] = make_ushort4(h8[4], h8[5], h8[6], h8[7]);
        *(ushort4*)&wfl[off]     = make_ushort4(l8[0], l8[1], l8[2], l8[3]);
        *(ushort4*)&wfl[off + 4] = make_ushort4(l8[4], l8[5], l8[6], l8[7]);
    } else {                                      // W2: 8 ks x 4 nb x 64 lanes
        int u = t - 8192;
        int ks = u >> 8, nb = (u >> 6) & 3;
        ushort h8[8];
        #pragma unroll
        for (int j = 0; j < 8; ++j) {
            int k = ks * 32 + quad * 8 + j;
            h8[j] = f2b(W2[k * N_CLASSES + nb * 16 + m]);
        }
        long off = ((long)(ks * 4 + nb) * 64 + lane) * 8;
        *(ushort4*)&wf2[off]     = make_ushort4(h8[0], h8[1], h8[2], h8[3]);
        *(ushort4*)&wf2[off + 4] = make_ushort4(h8[4], h8[5], h8[6], h8[7]);
    }
}

// ---------------- GEMM1: hs = dinv[row] * (x @ W1), fused split, rebalanced -
// Barrier-free (R0 dataflow). Wave = 32 rows x 128 cols, block = 4 waves =
// 64 rows x 256 cols (full HIDDEN, grid.x=1 -> no cross-block re-conversion).
// Per wave K-step: 4 loads + 16 converts feed 48 MFMAs (1:1 VALU:MFMA).
// Same truncate-hi / RNE-lo split and MFMA order as R0 -> bit-identical.
__global__ __launch_bounds__(256)
void gemm1_mfma(const float* __restrict__ x,
                const ushort* __restrict__ wfh, const ushort* __restrict__ wfl,
                const float* __restrict__ dinv, ushort* __restrict__ hs)
{
    int tid = threadIdx.x;
    int lane = tid & 63;
    int wm = (tid >> 6) & 1;                 // 32-row half
    int wn = tid >> 7;                       // 128-col half
    int row0 = blockIdx.x * 64 + wm * 32;
    int nb0 = wn * 8;
    int m = lane & 15, quad = lane >> 4;

    f32x4 acc[2][8];
    #pragma unroll
    for (int i = 0; i < 2; ++i)
        #pragma unroll
        for (int j = 0; j < 8; ++j) acc[i][j] = (f32x4){0.f, 0.f, 0.f, 0.f};

    for (int ks = 0; ks < 8; ++ks) {
        bf16x8 ah[2], al[2];
        #pragma unroll
        for (int mf = 0; mf < 2; ++mf) {
            int rr = row0 + mf * 16 + m;
            rr = (rr < N_NODES) ? rr : (N_NODES - 1);   // clamp: x is exact-size
            const float* p = x + (long)rr * D_FEAT + ks * 32 + quad * 8;
            float4 v0 = *(const float4*)p;
            float4 v1 = *(const float4*)(p + 4);
            float vv[8] = {v0.x, v0.y, v0.z, v0.w, v1.x, v1.y, v1.z, v1.w};
            #pragma unroll
            for (int j = 0; j < 8; ++j) {
                unsigned u; __builtin_memcpy(&u, &vv[j], 4);
                ushort hh = (ushort)(u >> 16);           // truncate hi
                float hv = b2f(hh);
                ushort ll = f2b(vv[j] - hv);             // exact remainder, RNE
                ah[mf][j] = (short)hh;
                al[mf][j] = (short)ll;
            }
        }
        #pragma unroll
        for (int nbl = 0; nbl < 8; ++nbl) {
            long boff = ((long)(ks * 16 + nb0 + nbl) * 64 + lane) * 8;
            bf16x8 bh = *(const bf16x8*)(wfh + boff);
            bf16x8 bl = *(const bf16x8*)(wfl + boff);
            #pragma unroll
            for (int mf = 0; mf < 2; ++mf) {
                acc[mf][nbl] = __builtin_amdgcn_mfma_f32_16x16x32_bf16(ah[mf], bh, acc[mf][nbl], 0, 0, 0);
                acc[mf][nbl] = __builtin_amdgcn_mfma_f32_16x16x32_bf16(ah[mf], bl, acc[mf][nbl], 0, 0, 0);
                acc[mf][nbl] = __builtin_amdgcn_mfma_f32_16x16x32_bf16(al[mf], bh, acc[mf][nbl], 0, 0, 0);
            }
        }
    }

    #pragma unroll
    for (int mf = 0; mf < 2; ++mf)
        #pragma unroll
        for (int reg = 0; reg < 4; ++reg) {
            int row = row0 + mf * 16 + quad * 4 + reg;
            if (row < N_NODES) {
                float dv = dinv[row];
                #pragma unroll
                for (int nbl = 0; nbl < 8; ++nbl)
                    hs[(long)row * HIDDEN + (nb0 + nbl) * 16 + m] = f2b(acc[mf][nbl][reg] * dv);
            }
        }
}

// ---------------- GEMM2: h2 = r1s @ W2 (bf16 single) ----------------
__global__ __launch_bounds__(256)
void gemm2_mfma(const ushort* __restrict__ r1s, const ushort* __restrict__ wf,
                ushort* __restrict__ h2)
{
    int tid = threadIdx.x;
    int wv = tid >> 6, lane = tid & 63;
    int row0 = blockIdx.x * 256 + wv * 64;
    int m = lane & 15, quad = lane >> 4;

    f32x4 acc[4][4];
    #pragma unroll
    for (int i = 0; i < 4; ++i)
        #pragma unroll
        for (int j = 0; j < 4; ++j) acc[i][j] = (f32x4){0.f, 0.f, 0.f, 0.f};

    for (int ks = 0; ks < 8; ++ks) {
        bf16x8 a[4];
        #pragma unroll
        for (int mf = 0; mf < 4; ++mf) {
            long r = (long)(row0 + mf * 16 + m);
            a[mf] = *(const bf16x8*)(r1s + r * HIDDEN + ks * 32 + quad * 8);
        }
        #pragma unroll
        for (int nb = 0; nb < 4; ++nb) {
            bf16x8 b = *(const bf16x8*)(wf + ((long)(ks * 4 + nb) * 64 + lane) * 8);
            #pragma unroll
            for (int mf = 0; mf < 4; ++mf)
                acc[mf][nb] = __builtin_amdgcn_mfma_f32_16x16x32_bf16(a[mf], b, acc[mf][nb], 0, 0, 0);
        }
    }

    #pragma unroll
    for (int mf = 0; mf < 4; ++mf)
        #pragma unroll
        for (int reg = 0; reg < 4; ++reg) {
            int row = row0 + mf * 16 + quad * 4 + reg;
            if (row < N_NODES) {
                #pragma unroll
                for (int nb = 0; nb < 4; ++nb)
                    h2[(long)row * N_CLASSES + nb * 16 + m] = f2b(acc[mf][nb][reg]);
            }
        }
}

// ---------------- aggregate 256 feats bf16, unroll 8 ----------------
__global__ __launch_bounds__(256)
void agg256(const ushort* __restrict__ src, const int* __restrict__ offsets,
            const int* __restrict__ esrc, const float* __restrict__ dinv,
            const float* __restrict__ b1, ushort* __restrict__ dst)
{
    int wave = threadIdx.x >> 6, lane = threadIdx.x & 63;
    int v = blockIdx.x * 4 + wave;
    int c = lane << 2;
    ushort4 s = *(const ushort4*)&src[(long)v * 256 + c];
    float a0 = b2f(s.x), a1 = b2f(s.y), a2 = b2f(s.z), a3 = b2f(s.w);
    int e = offsets[v], end = offsets[v + 1];
    for (; e + 8 <= end; e += 8) {
        ushort4 u[8];
        #pragma unroll
        for (int j = 0; j < 8; ++j)
            u[j] = *(const ushort4*)&src[(long)esrc[e + j] * 256 + c];
        #pragma unroll
        for (int j = 0; j < 8; ++j) {
            a0 += b2f(u[j].x); a1 += b2f(u[j].y);
            a2 += b2f(u[j].z); a3 += b2f(u[j].w);
        }
    }
    for (; e < end; ++e) {
        ushort4 u = *(const ushort4*)&src[(long)esrc[e] * 256 + c];
        a0 += b2f(u.x); a1 += b2f(u.y); a2 += b2f(u.z); a3 += b2f(u.w);
    }
    float dv = dinv[v];
    float4 bb = *(const float4*)&b1[c];
    float r0 = dv * fmaxf(fmaf(dv, a0, bb.x), 0.f);
    float r1 = dv * fmaxf(fmaf(dv, a1, bb.y), 0.f);
    float r2 = dv * fmaxf(fmaf(dv, a2, bb.z), 0.f);
    float r3 = dv * fmaxf(fmaf(dv, a3, bb.w), 0.f);
    *(ushort4*)&dst[(long)v * 256 + c] = make_ushort4(f2b(r0), f2b(r1), f2b(r2), f2b(r3));
}

// ---------------- aggregate 64 feats bf16 -> fp32 out, unroll 8 -------------
__global__ __launch_bounds__(256)
void agg64b(const ushort* __restrict__ src, const int* __restrict__ offsets,
            const int* __restrict__ esrc, const float* __restrict__ dinv,
            const float* __restrict__ b2, float* __restrict__ out)
{
    int wave = threadIdx.x >> 6, lane = threadIdx.x & 63;
    int v = blockIdx.x * 4 + wave;
    float acc = b2f(src[(long)v * 64 + lane]);
    int e = offsets[v], end = offsets[v + 1];
    for (; e + 8 <= end; e += 8) {
        float a[8];
        #pragma unroll
        for (int j = 0; j < 8; ++j)
            a[j] = b2f(src[(long)esrc[e + j] * 64 + lane]);
        acc += ((a[0] + a[1]) + (a[2] + a[3])) + ((a[4] + a[5]) + (a[6] + a[7]));
    }
    for (; e < end; ++e) acc += b2f(src[(long)esrc[e] * 64 + lane]);
    out[(long)v * 64 + lane] = fmaf(dinv[v], acc, b2[lane]);
}

// ---------------- workspace layout (bytes, 16-aligned) ----------------
#define WS_DINV   0UL            // 400,000
#define WS_OFFS   400000UL       // 400,004
#define WS_BCNT   800016UL       // 391*4
#define WS_BBASE  801584UL       // 392*4
#define WS_BCUR   803152UL       // 391*4
#define WS_ESRC   804720UL       // 6,400,000
#define WS_BINS   7204720UL      // 6,400,000
#define WS_WF1H   13604720UL     // 131,072
#define WS_WF1L   13735792UL     // 131,072
#define WS_WF2    13866864UL     // 32,768
#define WS_HS1    13899632UL     // 51,216,384
#define WS_R1S    65148784UL     // 51,216,384
#define WS_H2     116397936UL    // 12,804,096 -> end ~129.2 MB

extern "C" void kernel_launch(void* const* d_in, const int* in_sizes, int n_in,
                              void* d_out, int out_size, void* d_ws, size_t ws_size,
                              hipStream_t stream)
{
    const float* x  = (const float*)d_in[0];
    const int*   ei = (const int*)d_in[1];
    const float* W1 = (const float*)d_in[2];
    const float* b1 = (const float*)d_in[3];
    const float* W2 = (const float*)d_in[4];
    const float* b2 = (const float*)d_in[5];
    float* out = (float*)d_out;

    const int* rows = ei;            // sources
    const int* cols = ei + N_EDGES;  // targets

    char* ws = (char*)d_ws;
    float*    dinv    = (float*)(ws + WS_DINV);
    int*      offsets = (int*)(ws + WS_OFFS);
    int*      bcnt    = (int*)(ws + WS_BCNT);
    int*      bbase   = (int*)(ws + WS_BBASE);
    int*      bcur    = (int*)(ws + WS_BCUR);
    int*      esrc    = (int*)(ws + WS_ESRC);
    unsigned* bins    = (unsigned*)(ws + WS_BINS);
    ushort*   wf1h    = (ushort*)(ws + WS_WF1H);
    ushort*   wf1l    = (ushort*)(ws + WS_WF1L);
    ushort*   wf2     = (ushort*)(ws + WS_WF2);
    ushort*   hs1     = (ushort*)(ws + WS_HS1);
    ushort*   r1s     = (ushort*)(ws + WS_R1S);
    ushort*   h2      = (ushort*)(ws + WS_H2);

    // --- weight fragment prep (also zeros bcnt; launched first) ---
    fragw<<<40, 256, 0, stream>>>(W1, wf1h, wf1l, W2, wf2, bcnt);

    // --- CSR build (bucketed) ---
    bin_count<<<512, 256, 0, stream>>>(cols, bcnt, N_EDGES);
    bucket_scan<<<1, 256, 0, stream>>>(bcnt, bbase, bcur, offsets);
    bin_scatter<<<(N_EDGES + TILE - 1) / TILE, 256, 0, stream>>>(rows, cols, bcur, bins, N_EDGES);
    bucket_fill<<<NBKT, 256, 0, stream>>>(bins, bbase, offsets, dinv, esrc);

    const int agg_grid = N_NODES / 4;

    // --- layer 1 ---
    gemm1_mfma<<<(N_NODES + 63) / 64, 256, 0, stream>>>(x, wf1h, wf1l, dinv, hs1);
    agg256<<<agg_grid, 256, 0, stream>>>(hs1, offsets, esrc, dinv, b1, r1s);

    // --- layer 2 ---
    gemm2_mfma<<<(N_NODES + 255) / 256, 256, 0, stream>>>(r1s, wf2, h2);
    agg64b<<<agg_grid, 256, 0, stream>>>(h2, offsets, esrc, dinv, b2, out);
}